// Round 7
// baseline (1228.521 us; speedup 1.0000x reference)
//
#include <hip/hip_runtime.h>
#include <hip/hip_bf16.h>

// Problem: x [32768,512] fp32, centroids [8192,512] fp32
#define N_ROWS 32768
#define DIM    512
#define K_CENT 8192

// Output (flat fp32): x_q [N*D] | loss [1] | indices-as-float [N]
#define LOSS_OFF 16777216u
#define IDX_OFF  16777217u

// Scratch carved from the x_q region of d_out (xh/ch always; cnorm/cand only
// when d_ws is too small for them):
#define XH_OFF_B   0u
#define CH_OFF_B   33554432u
#define CN_OFF_B   41943040u
#define CAND_OFF_B 41975808u

#define CAND_BYTES 2097152u
#define CN_BYTES   32768u

#define BM 128
#define BN 128
#define KHALF 4096           // columns per blockIdx.y half
#define NKT (KHALF / BN)     // 32
#define NH  2

typedef __bf16 bf16x8 __attribute__((ext_vector_type(8)));
typedef float  f32x4  __attribute__((ext_vector_type(4)));

__device__ __forceinline__ unsigned short f2bf(float f) {
    unsigned u = __float_as_uint(f);
    return (unsigned short)((u + 0x7fffu + ((u >> 16) & 1u)) >> 16);
}

// compare-exchange on (d,i) pairs, lexicographic
__device__ __forceinline__ void ce(float& da, int& ia, float& db, int& ib) {
    bool sw = (db < da) || (db == da && ib < ia);
    float td = sw ? db : da; int ti = sw ? ib : ia;
    float ud = sw ? da : db; int ui = sw ? ia : ib;
    da = td; ia = ti; db = ud; ib = ui;
}
__device__ __forceinline__ void lmin(float da, int ia, float db, int ib,
                                     float& od, int& oi) {
    bool sw = (db < da) || (db == da && ib < ia);
    od = sw ? db : da; oi = sw ? ib : ia;
}

// ---------------- k0: one-shot fp32 -> bf16(hi) conversion + c_norm
__global__ void __launch_bounds__(256) convert_kernel(const float* __restrict__ x,
                                                      const float* __restrict__ c,
                                                      unsigned short* __restrict__ xh,
                                                      unsigned short* __restrict__ ch,
                                                      float* __restrict__ cnp) {
    const int wave = threadIdx.x >> 6, lane = threadIdx.x & 63;
    const int gid = blockIdx.x * 4 + wave;
    if (gid < N_ROWS) {
        const float* p = x + (size_t)gid * DIM + lane * 8;
        float4 a = *(const float4*)p, b = *(const float4*)(p + 4);
        uint4 w;
        w.x = (unsigned)f2bf(a.x) | ((unsigned)f2bf(a.y) << 16);
        w.y = (unsigned)f2bf(a.z) | ((unsigned)f2bf(a.w) << 16);
        w.z = (unsigned)f2bf(b.x) | ((unsigned)f2bf(b.y) << 16);
        w.w = (unsigned)f2bf(b.z) | ((unsigned)f2bf(b.w) << 16);
        *(uint4*)(xh + (size_t)gid * DIM + lane * 8) = w;
    } else {
        const int cr = gid - N_ROWS;
        const float* p = c + (size_t)cr * DIM + lane * 8;
        float4 a = *(const float4*)p, b = *(const float4*)(p + 4);
        uint4 w;
        w.x = (unsigned)f2bf(a.x) | ((unsigned)f2bf(a.y) << 16);
        w.y = (unsigned)f2bf(a.z) | ((unsigned)f2bf(a.w) << 16);
        w.z = (unsigned)f2bf(b.x) | ((unsigned)f2bf(b.y) << 16);
        w.w = (unsigned)f2bf(b.z) | ((unsigned)f2bf(b.w) << 16);
        *(uint4*)(ch + (size_t)cr * DIM + lane * 8) = w;
        float s = a.x*a.x + a.y*a.y + a.z*a.z + a.w*a.w
                + b.x*b.x + b.y*b.y + b.z*b.z + b.w*b.w;
#pragma unroll
        for (int off = 32; off; off >>= 1) s += __shfl_down(s, off, 64);
        if (lane == 0) cnp[cr] = s;
    }
}

// ---------------- k1: bf16 MFMA proxy GEMM, direct-from-global fragments.
// grid (256, 2), 4 waves. NO LDS staging, NO K-loop barriers: x-tile (128KB)
// and the block's c-half (4MB) are L1/L2-resident; each wave loads its MFMA
// fragments straight to registers, ping-pong prefetched one K-step ahead.
// Compiler inserts fine-grained vmcnt waits (loads are compiler-visible).
// A raw s_barrier (no waitcnt!) every 4 K-steps bounds wave drift so twin
// waves reuse each other's fragment lines in L1.
__global__ void __launch_bounds__(256, 2) vq_main(const unsigned short* __restrict__ xh,
                                                  const unsigned short* __restrict__ ch,
                                                  const float* __restrict__ cnp,
                                                  float* __restrict__ cand) {
    __shared__ float sh_d[2][BM][4];                       // 4 KB (merge only)
    __shared__ int   sh_i[2][BM][4];                       // 4 KB

    const int tid  = threadIdx.x;
    const int wave = tid >> 6, lane = tid & 63;
    const int wm   = wave >> 1, wk = wave & 1;
    const int lr   = lane & 15, quad = lane >> 4;
    const int nbase = blockIdx.x * BM;
    const int h     = blockIdx.y;
    const int kc0   = h * KHALF;

    // per-fragment base pointers (row fixed per mt/t; K-offset added per step)
    const unsigned short* abase[4];
    const unsigned short* bbase[4];
#pragma unroll
    for (int t = 0; t < 4; ++t) {
        abase[t] = xh + (size_t)(nbase + wm * 64 + t * 16 + lr) * DIM + quad * 8;
        bbase[t] = ch + (size_t)(kc0 + wk * 64 + t * 16 + lr) * DIM + quad * 8;
    }

    float rd1[4][4], rd2[4][4];
    int   ri1[4][4], ri2[4][4];
#pragma unroll
    for (int mt = 0; mt < 4; ++mt)
#pragma unroll
        for (int r = 0; r < 4; ++r) {
            rd1[mt][r] = 1e30f; rd2[mt][r] = 1e30f;
            ri1[mt][r] = 0x7ffffff0; ri2[mt][r] = 0x7ffffff1;
        }

    // prime K-step 0 of kt 0
    bf16x8 ca[4], cb[4];
#pragma unroll
    for (int t = 0; t < 4; ++t) {
        ca[t] = *(const bf16x8*)(abase[t]);
        cb[t] = *(const bf16x8*)(bbase[t]);
    }

    for (int kt = 0; kt < NKT; ++kt) {
        const int kc = kc0 + kt * BN;
        const size_t bko = (size_t)kt * (BN * DIM);     // b row-block offset
        float cnv[4];
#pragma unroll
        for (int t = 0; t < 4; ++t) cnv[t] = cnp[kc + wk * 64 + t * 16 + lr];

        f32x4 acc[4][4];
#pragma unroll
        for (int mt = 0; mt < 4; ++mt)
#pragma unroll
            for (int t = 0; t < 4; ++t)
                acc[mt][t] = (f32x4){0.f, 0.f, 0.f, 0.f};

#pragma unroll
        for (int j = 0; j < 16; ++j) {
            // prefetch next K-step's fragments (next kt's ks=0 when j==15;
            // clamped re-read of valid memory on the final tail — unused)
            bf16x8 na[4], nb[4];
            if (j < 15) {
                const int ko = (j + 1) * 32;
#pragma unroll
                for (int t = 0; t < 4; ++t) {
                    na[t] = *(const bf16x8*)(abase[t] + ko);
                    nb[t] = *(const bf16x8*)(bbase[t] + bko + 65536 /*128*DIM*/ + ko
                                             - 65536 + (size_t)0 + 0 + (0));  // placeholder overwritten below
                }
                // (separate loop kept simple: b at same kt)
#pragma unroll
                for (int t = 0; t < 4; ++t)
                    nb[t] = *(const bf16x8*)(bbase[t] + bko + ko);
            } else {
                const int ktn = (kt + 1 < NKT) ? (kt + 1) : kt;   // clamp tail
                const size_t bkon = (size_t)ktn * (BN * DIM);
#pragma unroll
                for (int t = 0; t < 4; ++t) {
                    na[t] = *(const bf16x8*)(abase[t]);
                    nb[t] = *(const bf16x8*)(bbase[t] + bkon);
                }
            }
            // compute current K-step (compiler waits only on ca/cb here)
#pragma unroll
            for (int mt = 0; mt < 4; ++mt)
#pragma unroll
                for (int t = 0; t < 4; ++t)
                    acc[mt][t] = __builtin_amdgcn_mfma_f32_16x16x32_bf16(ca[mt], cb[t], acc[mt][t], 0, 0, 0);
#pragma unroll
            for (int t = 0; t < 4; ++t) { ca[t] = na[t]; cb[t] = nb[t]; }
            // drift-bounding rendezvous: raw barrier, NO waitcnt — loads
            // stay in flight, pipes keep flowing (not a drain barrier)
            if ((j & 3) == 3) __builtin_amdgcn_s_barrier();
        }

        // epilogue: proxy dist = c_norm - 2*S; running top-2 per (lane,row)
#pragma unroll
        for (int t = 0; t < 4; ++t) {
            const int col = kc + wk * 64 + t * 16 + lr;
#pragma unroll
            for (int mt = 0; mt < 4; ++mt)
#pragma unroll
                for (int r = 0; r < 4; ++r) {
                    float d = fmaf(-2.f, acc[mt][t][r], cnv[t]);
                    bool b1 = d < rd1[mt][r];
                    bool b2 = d < rd2[mt][r];
                    float o1 = rd1[mt][r]; int oi1 = ri1[mt][r];
                    rd2[mt][r] = b1 ? o1 : (b2 ? d : rd2[mt][r]);
                    ri2[mt][r] = b1 ? oi1 : (b2 ? col : ri2[mt][r]);
                    rd1[mt][r] = b1 ? d : o1;
                    ri1[mt][r] = b1 ? col : oi1;
                }
        }
    }

    // Merge 16 lanes/row (each holding sorted top-2) -> sorted top-4 per (wk,row)
#pragma unroll
    for (int mt = 0; mt < 4; ++mt)
#pragma unroll
        for (int r = 0; r < 4; ++r) {
            float a0 = rd1[mt][r], a1 = rd2[mt][r], a2 = 1e30f, a3 = 1e30f;
            int   i0 = ri1[mt][r], i1 = ri2[mt][r], i2 = 0x7ffffff2, i3 = 0x7ffffff3;
#pragma unroll
            for (int s = 1; s < 16; s <<= 1) {
                float p0 = __shfl_xor(a0, s, 64), p1 = __shfl_xor(a1, s, 64);
                float p2 = __shfl_xor(a2, s, 64), p3 = __shfl_xor(a3, s, 64);
                int   q0 = __shfl_xor(i0, s, 64), q1 = __shfl_xor(i1, s, 64);
                int   q2 = __shfl_xor(i2, s, 64), q3 = __shfl_xor(i3, s, 64);
                float l0, l1, l2, l3; int m0, m1, m2, m3;
                lmin(a0, i0, p3, q3, l0, m0);
                lmin(a1, i1, p2, q2, l1, m1);
                lmin(a2, i2, p1, q1, l2, m2);
                lmin(a3, i3, p0, q0, l3, m3);
                ce(l0, m0, l2, m2); ce(l1, m1, l3, m3);
                ce(l0, m0, l1, m1); ce(l2, m2, l3, m3);
                a0 = l0; a1 = l1; a2 = l2; a3 = l3;
                i0 = m0; i1 = m1; i2 = m2; i3 = m3;
            }
            if (lr == 0) {
                const int rl = wm * 64 + mt * 16 + quad * 4 + r;
                sh_d[wk][rl][0] = a0; sh_i[wk][rl][0] = i0;
                sh_d[wk][rl][1] = a1; sh_i[wk][rl][1] = i1;
                sh_d[wk][rl][2] = a2; sh_i[wk][rl][2] = i2;
                sh_d[wk][rl][3] = a3; sh_i[wk][rl][3] = i3;
            }
        }
    __syncthreads();

    // Cross-wk merge: two sorted-4 lists -> this half's true top-4 per row.
    if (tid < BM) {
        float a0 = sh_d[0][tid][0], a1 = sh_d[0][tid][1];
        float a2 = sh_d[0][tid][2], a3 = sh_d[0][tid][3];
        int   i0 = sh_i[0][tid][0], i1 = sh_i[0][tid][1];
        int   i2 = sh_i[0][tid][2], i3 = sh_i[0][tid][3];
        float b0 = sh_d[1][tid][0], b1 = sh_d[1][tid][1];
        float b2 = sh_d[1][tid][2], b3 = sh_d[1][tid][3];
        int   j0 = sh_i[1][tid][0], j1 = sh_i[1][tid][1];
        int   j2 = sh_i[1][tid][2], j3 = sh_i[1][tid][3];
        float l0, l1, l2, l3; int m0, m1, m2, m3;
        lmin(a0, i0, b3, j3, l0, m0);
        lmin(a1, i1, b2, j2, l1, m1);
        lmin(a2, i2, b1, j1, l2, m2);
        lmin(a3, i3, b0, j0, l3, m3);
        ce(l0, m0, l2, m2); ce(l1, m1, l3, m3);
        ce(l0, m0, l1, m1); ce(l2, m2, l3, m3);
        float* cell = cand + ((size_t)(nbase + tid) * NH + h) * 8;
        cell[0] = l0; cell[1] = (float)m0;
        cell[2] = l1; cell[3] = (float)m1;
        cell[4] = l2; cell[5] = (float)m2;
        cell[6] = l3; cell[7] = (float)m3;
    }
}

// ---------------- k2: fp64-exact refine over 8 candidates; idx + loss
// (+ fused x_q write when cand lives in d_ws, so no aliasing with x_q)
__global__ void __launch_bounds__(256) vq_refine(const float* __restrict__ x,
                                                 const float* __restrict__ cg,
                                                 const float* __restrict__ cand,
                                                 float* __restrict__ outp,
                                                 int write_xq) {
    __shared__ double ls[4];
    const int wave = threadIdx.x >> 6, lane = threadIdx.x & 63;
    const int n = blockIdx.x * 4 + wave;
    const float* cell = cand + (size_t)n * 16;
    int kid[8];
#pragma unroll
    for (int j = 0; j < 8; ++j) kid[j] = (int)cell[2 * j + 1];

    const float* xr = x + (size_t)n * DIM + lane * 8;
    float4 xa = *(const float4*)xr;
    float4 xb = *(const float4*)(xr + 4);

    // prefetch all 8 candidate rows (breaks the serial load-latency chain)
    float4 ca[8], cb[8];
#pragma unroll
    for (int j = 0; j < 8; ++j) {
        const float* cr = cg + (size_t)kid[j] * DIM + lane * 8;
        ca[j] = *(const float4*)cr;
        cb[j] = *(const float4*)(cr + 4);
    }

    double bd = 1e300; int bi = 0x7fffffff;
    float4 va = xa, vb = xb;
#pragma unroll
    for (int j = 0; j < 8; ++j) {
        const int k = kid[j];
        double s = 0.0, t;
        t = (double)xa.x - (double)ca[j].x; s += t * t;
        t = (double)xa.y - (double)ca[j].y; s += t * t;
        t = (double)xa.z - (double)ca[j].z; s += t * t;
        t = (double)xa.w - (double)ca[j].w; s += t * t;
        t = (double)xb.x - (double)cb[j].x; s += t * t;
        t = (double)xb.y - (double)cb[j].y; s += t * t;
        t = (double)xb.z - (double)cb[j].z; s += t * t;
        t = (double)xb.w - (double)cb[j].w; s += t * t;
#pragma unroll
        for (int off = 32; off; off >>= 1) s += __shfl_down(s, off, 64);
        s = __shfl(s, 0, 64);
        bool w = (s < bd) || (s == bd && k < bi);
        bd = w ? s : bd;
        bi = w ? k : bi;
        va.x = w ? ca[j].x : va.x; va.y = w ? ca[j].y : va.y;
        va.z = w ? ca[j].z : va.z; va.w = w ? ca[j].w : va.w;
        vb.x = w ? cb[j].x : vb.x; vb.y = w ? cb[j].y : vb.y;
        vb.z = w ? cb[j].z : vb.z; vb.w = w ? cb[j].w : vb.w;
    }
    if (write_xq) {
        float* row = outp + (size_t)n * DIM + lane * 8;
        *(float4*)row = va;
        *(float4*)(row + 4) = vb;
    }
    if (lane == 0) { outp[IDX_OFF + n] = (float)bi; ls[wave] = bd; }
    __syncthreads();
    if (threadIdx.x == 0)
        atomicAdd(outp + LOSS_OFF,
                  (float)((ls[0] + ls[1] + ls[2] + ls[3]) * (1.25 / 16777216.0)));
}

// ---------------- k3 (fallback only): gather x_q from final indices
__global__ void __launch_bounds__(256) vq_gather(const float* __restrict__ cg,
                                                 float* __restrict__ outp) {
    const int wave = threadIdx.x >> 6, lane = threadIdx.x & 63;
    const int n = blockIdx.x * 4 + wave;
    const int k = (int)outp[IDX_OFF + n];
    const float* cr = cg + (size_t)k * DIM + lane * 8;
    float4 a = *(const float4*)cr;
    float4 b = *(const float4*)(cr + 4);
    float* row = outp + (size_t)n * DIM + lane * 8;
    *(float4*)row = a;
    *(float4*)(row + 4) = b;
}

extern "C" void kernel_launch(void* const* d_in, const int* in_sizes, int n_in,
                              void* d_out, int out_size, void* d_ws, size_t ws_size,
                              hipStream_t stream) {
    const float* x   = (const float*)d_in[0];
    const float* cen = (const float*)d_in[1];
    float* out = (float*)d_out;

    unsigned short* xh  = (unsigned short*)((char*)d_out + XH_OFF_B);
    unsigned short* chp = (unsigned short*)((char*)d_out + CH_OFF_B);

    // Prefer workspace for cand+cnorm: lets refine write x_q directly (no
    // aliasing with the cand region). Fallback: old d_out layout + gather.
    const int fused = (d_ws != nullptr) && (ws_size >= (size_t)(CAND_BYTES + CN_BYTES));
    float* cand = fused ? (float*)d_ws
                        : (float*)((char*)d_out + CAND_OFF_B);
    float* cnp  = fused ? (float*)((char*)d_ws + CAND_BYTES)
                        : (float*)((char*)d_out + CN_OFF_B);

    hipMemsetAsync((void*)(out + LOSS_OFF), 0, sizeof(float), stream);
    convert_kernel<<<(N_ROWS + K_CENT) / 4, 256, 0, stream>>>(x, cen, xh, chp, cnp);
    dim3 g2(N_ROWS / BM, NH);
    vq_main<<<g2, 256, 0, stream>>>(xh, chp, cnp, cand);
    vq_refine<<<N_ROWS / 4, 256, 0, stream>>>(x, cen, cand, out, fused);
    if (!fused) vq_gather<<<N_ROWS / 4, 256, 0, stream>>>(cen, out);
}

// Round 8
// 690.088 us; speedup vs baseline: 1.7802x; 1.7802x over previous
//
#include <hip/hip_runtime.h>
#include <hip/hip_bf16.h>

// Problem: x [32768,512] fp32, centroids [8192,512] fp32
#define N_ROWS 32768
#define DIM    512
#define K_CENT 8192

// Output (flat fp32): x_q [N*D] | loss [1] | indices-as-float [N]
#define LOSS_OFF 16777216u
#define IDX_OFF  16777217u

// Scratch carved from the x_q region of d_out (xh/ch always; cnorm/cand only
// when d_ws is too small for them):
#define XH_OFF_B   0u
#define CH_OFF_B   33554432u
#define CN_OFF_B   41943040u
#define CAND_OFF_B 41975808u

#define CAND_BYTES 1048576u
#define CN_BYTES   32768u

#define BM 128
#define BN 256               // centroid cols per kt tile
#define KHALF 4096           // cols per blockIdx.y half
#define NKT (KHALF / BN)     // 16
#define NH  2
#define NSTEP (NKT * 16)     // 256 contraction slots (16 per kt, 32 dims each)

typedef __bf16 bf16x8 __attribute__((ext_vector_type(8)));
typedef float  f32x4  __attribute__((ext_vector_type(4)));

__device__ __forceinline__ unsigned short f2bf(float f) {
    unsigned u = __float_as_uint(f);
    return (unsigned short)((u + 0x7fffu + ((u >> 16) & 1u)) >> 16);
}

__device__ __forceinline__ unsigned umn(unsigned a, unsigned b) { return a < b ? a : b; }
__device__ __forceinline__ unsigned umx(unsigned a, unsigned b) { return a > b ? a : b; }

// Async global->LDS, 16B per lane. LDS dest = wave-uniform base + lane*16;
// GLOBAL src is per-lane.
__device__ __forceinline__ void glds16(void* lds, const void* g) {
    __builtin_amdgcn_global_load_lds(
        (const __attribute__((address_space(1))) unsigned*)g,
        (__attribute__((address_space(3))) unsigned*)lds, 16, 0, 0);
}

// ---------------- k0: one-shot fp32 -> bf16(hi) conversion + c_norm
__global__ void __launch_bounds__(256) convert_kernel(const float* __restrict__ x,
                                                      const float* __restrict__ c,
                                                      unsigned short* __restrict__ xh,
                                                      unsigned short* __restrict__ ch,
                                                      float* __restrict__ cnp) {
    const int wave = threadIdx.x >> 6, lane = threadIdx.x & 63;
    const int gid = blockIdx.x * 4 + wave;
    if (gid < N_ROWS) {
        const float* p = x + (size_t)gid * DIM + lane * 8;
        float4 a = *(const float4*)p, b = *(const float4*)(p + 4);
        uint4 w;
        w.x = (unsigned)f2bf(a.x) | ((unsigned)f2bf(a.y) << 16);
        w.y = (unsigned)f2bf(a.z) | ((unsigned)f2bf(a.w) << 16);
        w.z = (unsigned)f2bf(b.x) | ((unsigned)f2bf(b.y) << 16);
        w.w = (unsigned)f2bf(b.z) | ((unsigned)f2bf(b.w) << 16);
        *(uint4*)(xh + (size_t)gid * DIM + lane * 8) = w;
    } else {
        const int cr = gid - N_ROWS;
        const float* p = c + (size_t)cr * DIM + lane * 8;
        float4 a = *(const float4*)p, b = *(const float4*)(p + 4);
        uint4 w;
        w.x = (unsigned)f2bf(a.x) | ((unsigned)f2bf(a.y) << 16);
        w.y = (unsigned)f2bf(a.z) | ((unsigned)f2bf(a.w) << 16);
        w.z = (unsigned)f2bf(b.x) | ((unsigned)f2bf(b.y) << 16);
        w.w = (unsigned)f2bf(b.z) | ((unsigned)f2bf(b.w) << 16);
        *(uint4*)(ch + (size_t)cr * DIM + lane * 8) = w;
        float s = a.x*a.x + a.y*a.y + a.z*a.z + a.w*a.w
                + b.x*b.x + b.y*b.y + b.z*b.z + b.w*b.w;
#pragma unroll
        for (int off = 32; off; off >>= 1) s += __shfl_down(s, off, 64);
        if (lane == 0) cnp[cr] = s;
    }
}

// ---------------- k1: bf16 MFMA proxy GEMM, 128x256 block / 64x128 per wave.
// grid (256, 2), 4 waves. Ring-3 LDS slots (24KB: x[128][32]+c[256][32]),
// counted vmcnt(6) (never drained in-loop), one barrier per 32-dim step —
// round-6-proven schedule; the 64x128 wave tile cuts LDS bytes/FLOP 1.33x
// (1/32 -> 1/42.7) so the LDS port is no longer the floor.
// Top-k state packed into sortable u32 keys: key = sortable(d)&~0x1FFF | col
// (13 idx bits; truncation ~= bf16 proxy noise; refine uses indices only).
__global__ void __launch_bounds__(256, 2) vq_main(const unsigned short* __restrict__ xh,
                                                  const unsigned short* __restrict__ ch,
                                                  const float* __restrict__ cnp,
                                                  float* __restrict__ cand) {
    __shared__ __align__(16) unsigned short xs[3 * 4096];   // 3 ring x 8 KB
    __shared__ __align__(16) unsigned short cs[3 * 8192];   // 3 ring x 16 KB
    __shared__ unsigned sh_k[2][BM][4];                     // 4 KB (merge)

    const int tid  = threadIdx.x;
    const int wave = tid >> 6, lane = tid & 63;
    const int wm   = wave >> 1, wk = wave & 1;
    const int lr   = lane & 15, quad = lane >> 4;
    const int nbase = blockIdx.x * BM;
    const int h     = blockIdx.y;
    const int kc0   = h * KHALF;

    // staging lane geometry (round-6-proven swizzle): call covers 16 rows;
    // lane -> (row = lane>>2, phys 16B-slot = lane&3); source slot
    // pre-swizzled with the involution the read side applies.
    const int srow16 = lane >> 2;
    const int sswz   = (lane & 3) ^ ((lane >> 3) & 3);
    const unsigned short* xg0 = xh + (size_t)(nbase + wave * 32 + srow16) * DIM + sswz * 8;
    const unsigned short* cg0 = ch + (size_t)(kc0 + wave * 64 + srow16) * DIM + sswz * 8;

    unsigned short* xw = xs + wave * 1024;   // + ring*4096 + g*512
    unsigned short* cw = cs + wave * 2048;   // + ring*8192 + g*512

#define STAGE(ring, sn_) do {                                                \
        const int ktn_ = (sn_) >> 4;                                         \
        const int dd_  = ((sn_) & 15) * 32;                                  \
        unsigned short* xd_ = xw + (ring) * 4096;                            \
        unsigned short* cd_ = cw + (ring) * 8192;                            \
        const unsigned short* xsrc_ = xg0 + dd_;                             \
        const unsigned short* csrc_ = cg0 + (size_t)ktn_ * (BN * DIM) + dd_; \
        glds16(xd_,        xsrc_);                                           \
        glds16(xd_ + 512,  xsrc_ + 16 * DIM);                                \
        glds16(cd_,        csrc_);                                           \
        glds16(cd_ + 512,  csrc_ + 16 * DIM);                                \
        glds16(cd_ + 1024, csrc_ + 32 * DIM);                                \
        glds16(cd_ + 1536, csrc_ + 48 * DIM);                                \
    } while (0)

    // fragment read offsets (bytes within a ring slot), swizzled
    const int sw = (quad ^ ((lr >> 1) & 3)) << 4;
    int aoff[4], boff[8];
#pragma unroll
    for (int mt = 0; mt < 4; ++mt) aoff[mt] = (wm * 64 + mt * 16 + lr) * 64 + sw;
#pragma unroll
    for (int t = 0; t < 8; ++t)    boff[t]  = (wk * 128 + t * 16 + lr) * 64 + sw;

    unsigned k1[4][4], k2[4][4];
#pragma unroll
    for (int mt = 0; mt < 4; ++mt)
#pragma unroll
        for (int r = 0; r < 4; ++r) { k1[mt][r] = 0xFFFFFFFFu; k2[mt][r] = 0xFFFFFFFFu; }

    // prologue: stage slots 0,1
    STAGE(0, 0);
    STAGE(1, 1);
    int rr = 0, rw = 2;

    for (int kt = 0; kt < NKT; ++kt) {
        const int kc = kc0 + kt * BN;
        float cnv[8];
#pragma unroll
        for (int t = 0; t < 8; ++t) cnv[t] = cnp[kc + wk * 128 + t * 16 + lr];

        f32x4 acc[4][8];
#pragma unroll
        for (int mt = 0; mt < 4; ++mt)
#pragma unroll
            for (int t = 0; t < 8; ++t)
                acc[mt][t] = (f32x4){0.f, 0.f, 0.f, 0.f};

#pragma unroll
        for (int j = 0; j < 16; ++j) {
            // slot s = kt*16+j ready once <=1 newer slot (6 calls) remains
            asm volatile("s_waitcnt vmcnt(6)" ::: "memory");
            __builtin_amdgcn_s_barrier();
            // issue slot s+2 (clamped tail re-stages slot 255 into idle
            // rings: valid addresses, never read — keeps vmcnt FIFO counted)
            int sn = kt * 16 + j + 2;
            if (sn > NSTEP - 1) sn = NSTEP - 1;
            STAGE(rw, sn);
            // compute slot s from ring rr
            const char* xb = (const char*)xs + rr * 8192;
            const char* cb = (const char*)cs + rr * 16384;
            bf16x8 af[4];
#pragma unroll
            for (int mt = 0; mt < 4; ++mt)
                af[mt] = *(const bf16x8*)(xb + aoff[mt]);
#pragma unroll
            for (int t = 0; t < 8; ++t) {
                bf16x8 bf = *(const bf16x8*)(cb + boff[t]);
#pragma unroll
                for (int mt = 0; mt < 4; ++mt)
                    acc[mt][t] = __builtin_amdgcn_mfma_f32_16x16x32_bf16(af[mt], bf, acc[mt][t], 0, 0, 0);
            }
            rr = (rr == 2) ? 0 : rr + 1;
            rw = (rw == 2) ? 0 : rw + 1;
        }

        // epilogue: d = c_norm - 2*S; packed-key top-2 per (lane,row).
        // Overlaps the in-flight prefetch of the next kt's slots.
#pragma unroll
        for (int t = 0; t < 8; ++t) {
            const unsigned colb = (unsigned)(kc + wk * 128 + t * 16 + lr);
#pragma unroll
            for (int mt = 0; mt < 4; ++mt)
#pragma unroll
                for (int r = 0; r < 4; ++r) {
                    float d = fmaf(-2.f, acc[mt][t][r], cnv[t]);
                    unsigned u = __float_as_uint(d);
                    u ^= ((unsigned)((int)u >> 31)) | 0x80000000u;   // sortable
                    unsigned key = (u & 0xFFFFE000u) | colb;
                    unsigned o1 = k1[mt][r];
                    k1[mt][r] = umn(key, o1);
                    k2[mt][r] = umn(umx(key, o1), k2[mt][r]);
                }
        }
    }
#undef STAGE

    // Merge 16 lanes/row (each sorted top-2 keys) -> sorted top-4 per (wk,row)
#pragma unroll
    for (int mt = 0; mt < 4; ++mt)
#pragma unroll
        for (int r = 0; r < 4; ++r) {
            unsigned a0 = k1[mt][r], a1 = k2[mt][r];
            unsigned a2 = 0xFFFFFFFFu, a3 = 0xFFFFFFFFu;
#pragma unroll
            for (int s = 1; s < 16; s <<= 1) {
                unsigned p0 = (unsigned)__shfl_xor((int)a0, s, 64);
                unsigned p1 = (unsigned)__shfl_xor((int)a1, s, 64);
                unsigned p2 = (unsigned)__shfl_xor((int)a2, s, 64);
                unsigned p3 = (unsigned)__shfl_xor((int)a3, s, 64);
                unsigned l0 = umn(a0, p3), l1 = umn(a1, p2);
                unsigned l2 = umn(a2, p1), l3 = umn(a3, p0);
                unsigned c0 = umn(l0, l2), c2 = umx(l0, l2);
                unsigned c1 = umn(l1, l3), c3 = umx(l1, l3);
                a0 = umn(c0, c1); a1 = umx(c0, c1);
                a2 = umn(c2, c3); a3 = umx(c2, c3);
            }
            if (lr == 0) {
                const int rl = wm * 64 + mt * 16 + quad * 4 + r;
                sh_k[wk][rl][0] = a0; sh_k[wk][rl][1] = a1;
                sh_k[wk][rl][2] = a2; sh_k[wk][rl][3] = a3;
            }
        }
    __syncthreads();

    // Cross-wk merge: two sorted-4 -> this half's top-4; emit indices.
    if (tid < BM) {
        unsigned a0 = sh_k[0][tid][0], a1 = sh_k[0][tid][1];
        unsigned a2 = sh_k[0][tid][2], a3 = sh_k[0][tid][3];
        unsigned b0 = sh_k[1][tid][0], b1 = sh_k[1][tid][1];
        unsigned b2 = sh_k[1][tid][2], b3 = sh_k[1][tid][3];
        unsigned l0 = umn(a0, b3), l1 = umn(a1, b2);
        unsigned l2 = umn(a2, b1), l3 = umn(a3, b0);
        unsigned c0 = umn(l0, l2), c2 = umx(l0, l2);
        unsigned c1 = umn(l1, l3), c3 = umx(l1, l3);
        unsigned m0 = umn(c0, c1), m1 = umx(c0, c1);
        unsigned m2 = umn(c2, c3), m3 = umx(c2, c3);
        float4 v;
        v.x = (float)(m0 & 0x1FFFu);
        v.y = (float)(m1 & 0x1FFFu);
        v.z = (float)(m2 & 0x1FFFu);
        v.w = (float)(m3 & 0x1FFFu);
        *(float4*)(cand + (size_t)(nbase + tid) * 8 + h * 4) = v;
    }
}

// ---------------- k2: fp64-exact refine over 8 candidate indices; idx + loss
// (+ fused x_q write when cand lives in d_ws, so no aliasing with x_q)
__global__ void __launch_bounds__(256) vq_refine(const float* __restrict__ x,
                                                 const float* __restrict__ cg,
                                                 const float* __restrict__ cand,
                                                 float* __restrict__ outp,
                                                 int write_xq) {
    __shared__ double ls[4];
    const int wave = threadIdx.x >> 6, lane = threadIdx.x & 63;
    const int n = blockIdx.x * 4 + wave;
    const float* cell = cand + (size_t)n * 8;
    int kid[8];
#pragma unroll
    for (int j = 0; j < 8; ++j) kid[j] = (int)cell[j];

    const float* xr = x + (size_t)n * DIM + lane * 8;
    float4 xa = *(const float4*)xr;
    float4 xb = *(const float4*)(xr + 4);

    // prefetch all 8 candidate rows (breaks the serial load-latency chain)
    float4 ca[8], cb[8];
#pragma unroll
    for (int j = 0; j < 8; ++j) {
        const float* cr = cg + (size_t)kid[j] * DIM + lane * 8;
        ca[j] = *(const float4*)cr;
        cb[j] = *(const float4*)(cr + 4);
    }

    double bd = 1e300; int bi = 0x7fffffff;
    float4 va = xa, vb = xb;
#pragma unroll
    for (int j = 0; j < 8; ++j) {
        const int k = kid[j];
        double s = 0.0, t;
        t = (double)xa.x - (double)ca[j].x; s += t * t;
        t = (double)xa.y - (double)ca[j].y; s += t * t;
        t = (double)xa.z - (double)ca[j].z; s += t * t;
        t = (double)xa.w - (double)ca[j].w; s += t * t;
        t = (double)xb.x - (double)cb[j].x; s += t * t;
        t = (double)xb.y - (double)cb[j].y; s += t * t;
        t = (double)xb.z - (double)cb[j].z; s += t * t;
        t = (double)xb.w - (double)cb[j].w; s += t * t;
#pragma unroll
        for (int off = 32; off; off >>= 1) s += __shfl_down(s, off, 64);
        s = __shfl(s, 0, 64);
        bool w = (s < bd) || (s == bd && k < bi);
        bd = w ? s : bd;
        bi = w ? k : bi;
        va.x = w ? ca[j].x : va.x; va.y = w ? ca[j].y : va.y;
        va.z = w ? ca[j].z : va.z; va.w = w ? ca[j].w : va.w;
        vb.x = w ? cb[j].x : vb.x; vb.y = w ? cb[j].y : vb.y;
        vb.z = w ? cb[j].z : vb.z; vb.w = w ? cb[j].w : vb.w;
    }
    if (write_xq) {
        float* row = outp + (size_t)n * DIM + lane * 8;
        *(float4*)row = va;
        *(float4*)(row + 4) = vb;
    }
    if (lane == 0) { outp[IDX_OFF + n] = (float)bi; ls[wave] = bd; }
    __syncthreads();
    if (threadIdx.x == 0)
        atomicAdd(outp + LOSS_OFF,
                  (float)((ls[0] + ls[1] + ls[2] + ls[3]) * (1.25 / 16777216.0)));
}

// ---------------- k3 (fallback only): gather x_q from final indices
__global__ void __launch_bounds__(256) vq_gather(const float* __restrict__ cg,
                                                 float* __restrict__ outp) {
    const int wave = threadIdx.x >> 6, lane = threadIdx.x & 63;
    const int n = blockIdx.x * 4 + wave;
    const int k = (int)outp[IDX_OFF + n];
    const float* cr = cg + (size_t)k * DIM + lane * 8;
    float4 a = *(const float4*)cr;
    float4 b = *(const float4*)(cr + 4);
    float* row = outp + (size_t)n * DIM + lane * 8;
    *(float4*)row = a;
    *(float4*)(row + 4) = b;
}

extern "C" void kernel_launch(void* const* d_in, const int* in_sizes, int n_in,
                              void* d_out, int out_size, void* d_ws, size_t ws_size,
                              hipStream_t stream) {
    const float* x   = (const float*)d_in[0];
    const float* cen = (const float*)d_in[1];
    float* out = (float*)d_out;

    unsigned short* xh  = (unsigned short*)((char*)d_out + XH_OFF_B);
    unsigned short* chp = (unsigned short*)((char*)d_out + CH_OFF_B);

    // Prefer workspace for cand+cnorm: lets refine write x_q directly (no
    // aliasing with the cand region). Fallback: old d_out layout + gather.
    const int fused = (d_ws != nullptr) && (ws_size >= (size_t)(CAND_BYTES + CN_BYTES));
    float* cand = fused ? (float*)d_ws
                        : (float*)((char*)d_out + CAND_OFF_B);
    float* cnp  = fused ? (float*)((char*)d_ws + CAND_BYTES)
                        : (float*)((char*)d_out + CN_OFF_B);

    hipMemsetAsync((void*)(out + LOSS_OFF), 0, sizeof(float), stream);
    convert_kernel<<<(N_ROWS + K_CENT) / 4, 256, 0, stream>>>(x, cen, xh, chp, cnp);
    dim3 g2(N_ROWS / BM, NH);
    vq_main<<<g2, 256, 0, stream>>>(xh, chp, cnp, cand);
    vq_refine<<<N_ROWS / 4, 256, 0, stream>>>(x, cen, cand, out, fused);
    if (!fused) vq_gather<<<N_ROWS / 4, 256, 0, stream>>>(cen, out);
}

// Round 9
// 614.526 us; speedup vs baseline: 1.9991x; 1.1230x over previous
//
#include <hip/hip_runtime.h>
#include <hip/hip_bf16.h>

// Problem: x [32768,512] fp32, centroids [8192,512] fp32
#define N_ROWS 32768
#define DIM    512
#define K_CENT 8192

// Output (flat fp32): x_q [N*D] | loss [1] | indices-as-float [N]
#define LOSS_OFF 16777216u
#define IDX_OFF  16777217u

// Scratch carved from the x_q region of d_out (xh/ch always; cnorm/cand only
// when d_ws is too small for them):
#define XH_OFF_B   0u
#define CH_OFF_B   33554432u
#define CN_OFF_B   41943040u
#define CAND_OFF_B 41975808u

#define CAND_BYTES 1048576u
#define CN_BYTES   32768u

#define BM 128
#define BN 128
#define KHALF 4096           // columns per blockIdx.y half
#define NKT (KHALF / BN)     // 32
#define NH  2
#define NSTEP (NKT * 16)     // 512 contraction slots (16 per kt, 32 dims each)

typedef __bf16 bf16x8 __attribute__((ext_vector_type(8)));
typedef float  f32x4  __attribute__((ext_vector_type(4)));

__device__ __forceinline__ unsigned short f2bf(float f) {
    unsigned u = __float_as_uint(f);
    return (unsigned short)((u + 0x7fffu + ((u >> 16) & 1u)) >> 16);
}

__device__ __forceinline__ unsigned umn(unsigned a, unsigned b) { return a < b ? a : b; }
__device__ __forceinline__ unsigned umx(unsigned a, unsigned b) { return a > b ? a : b; }

// Async global->LDS, 16B per lane. LDS dest = wave-uniform base + lane*16;
// GLOBAL src is per-lane.
__device__ __forceinline__ void glds16(void* lds, const void* g) {
    __builtin_amdgcn_global_load_lds(
        (const __attribute__((address_space(1))) unsigned*)g,
        (__attribute__((address_space(3))) unsigned*)lds, 16, 0, 0);
}

// ---------------- k0: one-shot fp32 -> bf16(hi) conversion + c_norm
__global__ void __launch_bounds__(256) convert_kernel(const float* __restrict__ x,
                                                      const float* __restrict__ c,
                                                      unsigned short* __restrict__ xh,
                                                      unsigned short* __restrict__ ch,
                                                      float* __restrict__ cnp) {
    const int wave = threadIdx.x >> 6, lane = threadIdx.x & 63;
    const int gid = blockIdx.x * 4 + wave;
    if (gid < N_ROWS) {
        const float* p = x + (size_t)gid * DIM + lane * 8;
        float4 a = *(const float4*)p, b = *(const float4*)(p + 4);
        uint4 w;
        w.x = (unsigned)f2bf(a.x) | ((unsigned)f2bf(a.y) << 16);
        w.y = (unsigned)f2bf(a.z) | ((unsigned)f2bf(a.w) << 16);
        w.z = (unsigned)f2bf(b.x) | ((unsigned)f2bf(b.y) << 16);
        w.w = (unsigned)f2bf(b.z) | ((unsigned)f2bf(b.w) << 16);
        *(uint4*)(xh + (size_t)gid * DIM + lane * 8) = w;
    } else {
        const int cr = gid - N_ROWS;
        const float* p = c + (size_t)cr * DIM + lane * 8;
        float4 a = *(const float4*)p, b = *(const float4*)(p + 4);
        uint4 w;
        w.x = (unsigned)f2bf(a.x) | ((unsigned)f2bf(a.y) << 16);
        w.y = (unsigned)f2bf(a.z) | ((unsigned)f2bf(a.w) << 16);
        w.z = (unsigned)f2bf(b.x) | ((unsigned)f2bf(b.y) << 16);
        w.w = (unsigned)f2bf(b.z) | ((unsigned)f2bf(b.w) << 16);
        *(uint4*)(ch + (size_t)cr * DIM + lane * 8) = w;
        float s = a.x*a.x + a.y*a.y + a.z*a.z + a.w*a.w
                + b.x*b.x + b.y*b.y + b.z*b.z + b.w*b.w;
#pragma unroll
        for (int off = 32; off; off >>= 1) s += __shfl_down(s, off, 64);
        if (lane == 0) cnp[cr] = s;
    }
}

// ---------------- k1: bf16 MFMA proxy GEMM, ring-4 counted-vmcnt pipeline
// (round-6-proven) + T5 setprio around the MFMA cluster + packed-key top-k.
// grid (256, 2). Slot = 32-dim tile (x[128][32] + c[128][32], 16 KB).
// Per step: vmcnt(8) [2 slots stay in flight] -> barrier -> issue slot s+3
// (clamped at tail so FIFO counts stay exact) -> setprio(1) MFMA setprio(0).
// LDS 16B-slot swizzle: phys = quad ^ ((lr>>1)&3); source pre-swizzled with
// the same involution ((lane&3)^((lane>>3)&3)) so glds16 dest stays linear.
// Top-k state = sortable u32 keys: key = (sortable(d) & ~0x1FFF) | col.
// 13 idx bits; truncation (~1.0 abs at d~1e3) ~= bf16 proxy noise; refine
// is fp64-exact over the 8 candidate indices, so only the candidate SET
// matters (HW-validated in round 8: passed, absmax unchanged).
__global__ void __launch_bounds__(256, 2) vq_main(const unsigned short* __restrict__ xh,
                                                  const unsigned short* __restrict__ ch,
                                                  const float* __restrict__ cnp,
                                                  float* __restrict__ cand) {
    __shared__ __align__(16) unsigned short xs[4 * 4096];  // 4 ring slots x 8 KB
    __shared__ __align__(16) unsigned short cs[4 * 4096];  // 4 ring slots x 8 KB
    __shared__ unsigned sh_k[2][BM][4];                    // 4 KB (merge)

    const int tid  = threadIdx.x;
    const int wave = tid >> 6, lane = tid & 63;
    const int wm   = wave >> 1, wk = wave & 1;
    const int lr   = lane & 15, quad = lane >> 4;
    const int nbase = blockIdx.x * BM;
    const int h     = blockIdx.y;
    const int kc0   = h * KHALF;

    // staging lane geometry: call g covers rows [wave*32+g*16, +16), lane ->
    // (row = g*16 + (lane>>2), phys slot = lane&3), source slot pre-swizzled.
    const int srow16 = lane >> 2;
    const int sswz   = (lane & 3) ^ ((lane >> 3) & 3);
    const unsigned short* xg0 = xh + (size_t)(nbase + wave * 32 + srow16) * DIM + sswz * 8;
    const unsigned short* xg1 = xg0 + (size_t)16 * DIM;
    const unsigned short* cg0 = ch + (size_t)(kc0 + wave * 32 + srow16) * DIM + sswz * 8;

    unsigned short* xw = xs + wave * 1024;   // + ring*4096 + g*512
    unsigned short* cw = cs + wave * 1024;

#define STAGE(ring, ktn, dd) do {                                          \
        unsigned short* xd_ = xw + (ring) * 4096;                          \
        unsigned short* cd_ = cw + (ring) * 4096;                          \
        const unsigned short* cgk_ = cg0 + (size_t)(ktn) * (BN * DIM) + (dd); \
        glds16(xd_,       xg0 + (dd));                                     \
        glds16(xd_ + 512, xg1 + (dd));                                     \
        glds16(cd_,       cgk_);                                           \
        glds16(cd_ + 512, cgk_ + 16 * DIM);                                \
    } while (0)

    // fragment read offsets (bytes within a ring slot), swizzled
    int aoff[4], boff[4];
#pragma unroll
    for (int t = 0; t < 4; ++t) {
        const int sw = (quad ^ ((lr >> 1) & 3)) << 4;
        aoff[t] = (wm * 64 + t * 16 + lr) * 64 + sw;
        boff[t] = (wk * 64 + t * 16 + lr) * 64 + sw;
    }

    unsigned k1[4][4], k2[4][4];
#pragma unroll
    for (int mt = 0; mt < 4; ++mt)
#pragma unroll
        for (int r = 0; r < 4; ++r) { k1[mt][r] = 0xFFFFFFFFu; k2[mt][r] = 0xFFFFFFFFu; }

    // ---- prologue: stage slots 0..2, full drain once
    STAGE(0, 0, 0);
    STAGE(1, 0, 32);
    STAGE(2, 0, 64);
    asm volatile("s_waitcnt vmcnt(0)" ::: "memory");
    __builtin_amdgcn_s_barrier();

    for (int kt = 0; kt < NKT; ++kt) {
        const int kc = kc0 + kt * BN;
        // c_norm prefetch for this kt's epilogue (issued early; FIFO-older
        // than the slot loads staged below, so its wait can't drain them)
        float cnv[4];
#pragma unroll
        for (int t = 0; t < 4; ++t) cnv[t] = cnp[kc + wk * 64 + t * 16 + lr];

        f32x4 acc[4][4];
#pragma unroll
        for (int mt = 0; mt < 4; ++mt)
#pragma unroll
            for (int t = 0; t < 4; ++t)
                acc[mt][t] = (f32x4){0.f, 0.f, 0.f, 0.f};

#pragma unroll 4
        for (int j = 0; j < 16; ++j) {
            // slot s = kt*16 + j ready once at most 2 newer slots remain
            asm volatile("s_waitcnt vmcnt(8)" ::: "memory");
            __builtin_amdgcn_s_barrier();
            // issue slot s+3; at the very tail, re-stage the final slot into
            // the (already-consumed) ring entry: keeps the vmcnt FIFO count
            // exact so every wait above genuinely retires slot s.
            {
                int sn = kt * 16 + j + 3;
                if (sn > NSTEP - 1) sn = NSTEP - 1;
                STAGE((kt * 16 + j + 3) & 3, sn >> 4, (sn & 15) * 32);
            }
            // compute slot s from ring (j&3); T5: boost priority so the CU
            // scheduler keeps the matrix pipe fed while sibling waves issue
            // their ds_reads/stages (counted-vmcnt phase-split => T5 regime)
            const char* xb = (const char*)xs + (j & 3) * 8192;
            const char* cb = (const char*)cs + (j & 3) * 8192;
            bf16x8 bfr[4];
#pragma unroll
            for (int t = 0; t < 4; ++t)
                bfr[t] = *(const bf16x8*)(cb + boff[t]);
            __builtin_amdgcn_s_setprio(1);
#pragma unroll
            for (int mt = 0; mt < 4; ++mt) {
                bf16x8 a = *(const bf16x8*)(xb + aoff[mt]);
#pragma unroll
                for (int t = 0; t < 4; ++t)
                    acc[mt][t] = __builtin_amdgcn_mfma_f32_16x16x32_bf16(a, bfr[t], acc[mt][t], 0, 0, 0);
            }
            __builtin_amdgcn_s_setprio(0);
        }

        // epilogue: d = c_norm - 2*S; packed-key top-2 per (lane,row).
        // Overlaps the (still in-flight) prefetch of the next kt's slots.
#pragma unroll
        for (int t = 0; t < 4; ++t) {
            const unsigned colb = (unsigned)(kc + wk * 64 + t * 16 + lr);
#pragma unroll
            for (int mt = 0; mt < 4; ++mt)
#pragma unroll
                for (int r = 0; r < 4; ++r) {
                    float d = fmaf(-2.f, acc[mt][t][r], cnv[t]);
                    unsigned u = __float_as_uint(d);
                    u ^= ((unsigned)((int)u >> 31)) | 0x80000000u;   // sortable
                    unsigned key = (u & 0xFFFFE000u) | colb;
                    unsigned o1 = k1[mt][r];
                    k1[mt][r] = umn(key, o1);
                    k2[mt][r] = umn(umx(key, o1), k2[mt][r]);
                }
        }
    }
#undef STAGE

    // Merge 16 lanes/row (each sorted top-2 keys) -> sorted top-4 per (wk,row)
#pragma unroll
    for (int mt = 0; mt < 4; ++mt)
#pragma unroll
        for (int r = 0; r < 4; ++r) {
            unsigned a0 = k1[mt][r], a1 = k2[mt][r];
            unsigned a2 = 0xFFFFFFFFu, a3 = 0xFFFFFFFFu;
#pragma unroll
            for (int s = 1; s < 16; s <<= 1) {
                unsigned p0 = (unsigned)__shfl_xor((int)a0, s, 64);
                unsigned p1 = (unsigned)__shfl_xor((int)a1, s, 64);
                unsigned p2 = (unsigned)__shfl_xor((int)a2, s, 64);
                unsigned p3 = (unsigned)__shfl_xor((int)a3, s, 64);
                unsigned l0 = umn(a0, p3), l1 = umn(a1, p2);
                unsigned l2 = umn(a2, p1), l3 = umn(a3, p0);
                unsigned c0 = umn(l0, l2), c2 = umx(l0, l2);
                unsigned c1 = umn(l1, l3), c3 = umx(l1, l3);
                a0 = umn(c0, c1); a1 = umx(c0, c1);
                a2 = umn(c2, c3); a3 = umx(c2, c3);
            }
            if (lr == 0) {
                const int rl = wm * 64 + mt * 16 + quad * 4 + r;
                sh_k[wk][rl][0] = a0; sh_k[wk][rl][1] = a1;
                sh_k[wk][rl][2] = a2; sh_k[wk][rl][3] = a3;
            }
        }
    __syncthreads();

    // Cross-wk merge: two sorted-4 -> this half's top-4; emit indices.
    if (tid < BM) {
        unsigned a0 = sh_k[0][tid][0], a1 = sh_k[0][tid][1];
        unsigned a2 = sh_k[0][tid][2], a3 = sh_k[0][tid][3];
        unsigned b0 = sh_k[1][tid][0], b1 = sh_k[1][tid][1];
        unsigned b2 = sh_k[1][tid][2], b3 = sh_k[1][tid][3];
        unsigned l0 = umn(a0, b3), l1 = umn(a1, b2);
        unsigned l2 = umn(a2, b1), l3 = umn(a3, b0);
        unsigned c0 = umn(l0, l2), c2 = umx(l0, l2);
        unsigned c1 = umn(l1, l3), c3 = umx(l1, l3);
        unsigned m0 = umn(c0, c1), m1 = umx(c0, c1);
        unsigned m2 = umn(c2, c3), m3 = umx(c2, c3);
        float4 v;
        v.x = (float)(m0 & 0x1FFFu);
        v.y = (float)(m1 & 0x1FFFu);
        v.z = (float)(m2 & 0x1FFFu);
        v.w = (float)(m3 & 0x1FFFu);
        *(float4*)(cand + (size_t)(nbase + tid) * 8 + h * 4) = v;
    }
}

// ---------------- k2: fp64-exact refine over 8 candidate indices; idx + loss
// (+ fused x_q write when cand lives in d_ws, so no aliasing with x_q)
__global__ void __launch_bounds__(256) vq_refine(const float* __restrict__ x,
                                                 const float* __restrict__ cg,
                                                 const float* __restrict__ cand,
                                                 float* __restrict__ outp,
                                                 int write_xq) {
    __shared__ double ls[4];
    const int wave = threadIdx.x >> 6, lane = threadIdx.x & 63;
    const int n = blockIdx.x * 4 + wave;
    const float* cell = cand + (size_t)n * 8;
    int kid[8];
#pragma unroll
    for (int j = 0; j < 8; ++j) kid[j] = (int)cell[j];

    const float* xr = x + (size_t)n * DIM + lane * 8;
    float4 xa = *(const float4*)xr;
    float4 xb = *(const float4*)(xr + 4);

    // prefetch all 8 candidate rows (breaks the serial load-latency chain)
    float4 ca[8], cb[8];
#pragma unroll
    for (int j = 0; j < 8; ++j) {
        const float* cr = cg + (size_t)kid[j] * DIM + lane * 8;
        ca[j] = *(const float4*)cr;
        cb[j] = *(const float4*)(cr + 4);
    }

    double bd = 1e300; int bi = 0x7fffffff;
    float4 va = xa, vb = xb;
#pragma unroll
    for (int j = 0; j < 8; ++j) {
        const int k = kid[j];
        double s = 0.0, t;
        t = (double)xa.x - (double)ca[j].x; s += t * t;
        t = (double)xa.y - (double)ca[j].y; s += t * t;
        t = (double)xa.z - (double)ca[j].z; s += t * t;
        t = (double)xa.w - (double)ca[j].w; s += t * t;
        t = (double)xb.x - (double)cb[j].x; s += t * t;
        t = (double)xb.y - (double)cb[j].y; s += t * t;
        t = (double)xb.z - (double)cb[j].z; s += t * t;
        t = (double)xb.w - (double)cb[j].w; s += t * t;
#pragma unroll
        for (int off = 32; off; off >>= 1) s += __shfl_down(s, off, 64);
        s = __shfl(s, 0, 64);
        bool w = (s < bd) || (s == bd && k < bi);
        bd = w ? s : bd;
        bi = w ? k : bi;
        va.x = w ? ca[j].x : va.x; va.y = w ? ca[j].y : va.y;
        va.z = w ? ca[j].z : va.z; va.w = w ? ca[j].w : va.w;
        vb.x = w ? cb[j].x : vb.x; vb.y = w ? cb[j].y : vb.y;
        vb.z = w ? cb[j].z : vb.z; vb.w = w ? cb[j].w : vb.w;
    }
    if (write_xq) {
        float* row = outp + (size_t)n * DIM + lane * 8;
        *(float4*)row = va;
        *(float4*)(row + 4) = vb;
    }
    if (lane == 0) { outp[IDX_OFF + n] = (float)bi; ls[wave] = bd; }
    __syncthreads();
    if (threadIdx.x == 0)
        atomicAdd(outp + LOSS_OFF,
                  (float)((ls[0] + ls[1] + ls[2] + ls[3]) * (1.25 / 16777216.0)));
}

// ---------------- k3 (fallback only): gather x_q from final indices
__global__ void __launch_bounds__(256) vq_gather(const float* __restrict__ cg,
                                                 float* __restrict__ outp) {
    const int wave = threadIdx.x >> 6, lane = threadIdx.x & 63;
    const int n = blockIdx.x * 4 + wave;
    const int k = (int)outp[IDX_OFF + n];
    const float* cr = cg + (size_t)k * DIM + lane * 8;
    float4 a = *(const float4*)cr;
    float4 b = *(const float4*)(cr + 4);
    float* row = outp + (size_t)n * DIM + lane * 8;
    *(float4*)row = a;
    *(float4*)(row + 4) = b;
}

extern "C" void kernel_launch(void* const* d_in, const int* in_sizes, int n_in,
                              void* d_out, int out_size, void* d_ws, size_t ws_size,
                              hipStream_t stream) {
    const float* x   = (const float*)d_in[0];
    const float* cen = (const float*)d_in[1];
    float* out = (float*)d_out;

    unsigned short* xh  = (unsigned short*)((char*)d_out + XH_OFF_B);
    unsigned short* chp = (unsigned short*)((char*)d_out + CH_OFF_B);

    // Prefer workspace for cand+cnorm: lets refine write x_q directly (no
    // aliasing with the cand region). Fallback: old d_out layout + gather.
    const int fused = (d_ws != nullptr) && (ws_size >= (size_t)(CAND_BYTES + CN_BYTES));
    float* cand = fused ? (float*)d_ws
                        : (float*)((char*)d_out + CAND_OFF_B);
    float* cnp  = fused ? (float*)((char*)d_ws + CAND_BYTES)
                        : (float*)((char*)d_out + CN_OFF_B);

    hipMemsetAsync((void*)(out + LOSS_OFF), 0, sizeof(float), stream);
    convert_kernel<<<(N_ROWS + K_CENT) / 4, 256, 0, stream>>>(x, cen, xh, chp, cnp);
    dim3 g2(N_ROWS / BM, NH);
    vq_main<<<g2, 256, 0, stream>>>(xh, chp, cnp, cand);
    vq_refine<<<N_ROWS / 4, 256, 0, stream>>>(x, cen, cand, out, fused);
    if (!fused) vq_gather<<<N_ROWS / 4, 256, 0, stream>>>(cen, out);
}